// Round 11
// baseline (164.491 us; speedup 1.0000x reference)
//
#include <hip/hip_runtime.h>
#include <math.h>

#define NTOT (128*128*128)
#define NBIN2 64                 // bins per axis (2 cells per bin)
#define BINS (NBIN2*NBIN2*NBIN2) // 262144
#define SCAN_BLOCKS 256

#define ZP 72                    // complex-mesh z pitch (>= 65, mult of 8)

#define PI_F      3.14159265358979323846f
#define TWO_PI_F  6.28318530717958647692f
#define FOUR_PI_F 12.5663706143591729539f

// ---------- helpers ----------

__device__ inline void inv3x3(const float* __restrict__ c, float* inv, float* detOut) {
    float a = c[0], b = c[1], cc = c[2];
    float d = c[3], e = c[4], f  = c[5];
    float g = c[6], h = c[7], i  = c[8];
    float A = e * i - f * h;
    float B = f * g - d * i;
    float C = d * h - e * g;
    float det = a * A + b * B + cc * C;
    float r = 1.0f / det;
    inv[0] = A * r;              inv[1] = (cc * h - b * i) * r;  inv[2] = (b * f - cc * e) * r;
    inv[3] = B * r;              inv[4] = (a * i - cc * g) * r;  inv[5] = (cc * d - a * f) * r;
    inv[6] = C * r;              inv[7] = (b * g - a * h) * r;   inv[8] = (a * e - b * d) * r;
    *detOut = det;
}

__device__ inline void w4(float x, float* w) {
    float x2 = x * x, x3 = x2 * x;
    w[0] = (1.0f  - 6.0f  * x + 12.0f * x2 - 8.0f  * x3) * (1.0f / 48.0f);
    w[1] = (23.0f - 30.0f * x - 12.0f * x2 + 24.0f * x3) * (1.0f / 48.0f);
    w[2] = (23.0f + 30.0f * x - 12.0f * x2 - 24.0f * x3) * (1.0f / 48.0f);
    w[3] = (1.0f  + 6.0f  * x + 12.0f * x2 + 8.0f  * x3) * (1.0f / 48.0f);
}

__device__ inline void atom_rel(const float* __restrict__ cell,
                                const float* __restrict__ pos, int t,
                                float* rx, float* ry, float* rz) {
    float inv[9]; float det;
    inv3x3(cell, inv, &det);
    float px = pos[3 * t], py = pos[3 * t + 1], pz = pos[3 * t + 2];
    *rx = (px * inv[0] + py * inv[3] + pz * inv[6]) * 128.0f;
    *ry = (px * inv[1] + py * inv[4] + pz * inv[7]) * 128.0f;
    *rz = (px * inv[2] + py * inv[5] + pz * inv[8]) * 128.0f;
}

__device__ inline int bin_of(float rx, float ry, float rz) {
    int ix = ((int)floorf(rx)) & 127;
    int iy = ((int)floorf(ry)) & 127;
    int iz = ((int)floorf(rz)) & 127;
    return ((((ix >> 1) << 6) | (iy >> 1)) << 6) | (iz >> 1);
}

// periodic wrap of a cell-units offset into (-64, 64]
__device__ inline float wrap128(float u) {
    u = (u > 64.0f) ? u - 128.0f : u;
    u = (u < -64.0f) ? u + 128.0f : u;
    return u;
}

// cubic B-spline M4 assignment weight (unnormalized: true weight = this / 6)
__device__ inline float bspline(float u) {
    float a = fabsf(u);
    float t = fmaxf(2.0f - a, 0.0f);
    float s = fmaxf(1.0f - a, 0.0f);
    return t * t * t - 4.0f * s * s * s;
}

// ---------- binning ----------

__global__ void zero_int_kernel(int* __restrict__ p, int n) {
    int i = blockIdx.x * blockDim.x + threadIdx.x;
    if (i < n) p[i] = 0;
}

__global__ void hist_kernel(const float* __restrict__ cell, const float* __restrict__ pos,
                            int* __restrict__ hist, int n) {
    int t = blockIdx.x * blockDim.x + threadIdx.x;
    if (t >= n) return;
    float rx, ry, rz;
    atom_rel(cell, pos, t, &rx, &ry, &rz);
    atomicAdd(&hist[bin_of(rx, ry, rz)], 1);
}

__global__ __launch_bounds__(256) void scan_local(const int4* __restrict__ hist4,
                                                  int4* __restrict__ off4,
                                                  int* __restrict__ partials) {
    const int b = blockIdx.x, t = threadIdx.x;
    const int idx = b * 256 + t;
    int4 h = hist4[idx];
    int s = h.x + h.y + h.z + h.w;
    int lane = t & 63, wv = t >> 6;
    int v = s;
    #pragma unroll
    for (int d = 1; d < 64; d <<= 1) {
        int o = __shfl_up(v, d, 64);
        if (lane >= d) v += o;
    }
    __shared__ int wsum[4];
    if (lane == 63) wsum[wv] = v;
    __syncthreads();
    int add = 0;
    #pragma unroll
    for (int k = 0; k < 4; ++k) if (k < wv) add += wsum[k];
    int run = add + v - s;
    int4 o4;
    o4.x = run; run += h.x;
    o4.y = run; run += h.y;
    o4.z = run; run += h.z;
    o4.w = run; run += h.w;
    off4[idx] = o4;
    if (t == 255) partials[b] = run;
}

__global__ __launch_bounds__(256) void scan_add(int4* __restrict__ hist4,
                                                int4* __restrict__ off4,
                                                const int* __restrict__ partials,
                                                int* __restrict__ offsets) {
    const int b = blockIdx.x, t = threadIdx.x;
    int lane = t & 63, wv = t >> 6;
    int v = (t < b) ? partials[t] : 0;
    #pragma unroll
    for (int d = 32; d >= 1; d >>= 1) v += __shfl_xor(v, d, 64);
    __shared__ int ws2[4];
    __shared__ int base_s;
    if (lane == 0) ws2[wv] = v;
    __syncthreads();
    if (t == 0) base_s = ws2[0] + ws2[1] + ws2[2] + ws2[3];
    __syncthreads();
    const int base = base_s;
    const int idx = b * 256 + t;
    int4 o4 = off4[idx];
    o4.x += base; o4.y += base; o4.z += base; o4.w += base;
    off4[idx]  = o4;
    hist4[idx] = o4;
    if (b == SCAN_BLOCKS - 1 && t == 255) offsets[BINS] = base + partials[b];
}

__global__ void reorder_kernel(const float* __restrict__ cell, const float* __restrict__ pos,
                               const float* __restrict__ q, int* __restrict__ cursor,
                               float4* __restrict__ sorted, int* __restrict__ sortedIdx, int n) {
    int t = blockIdx.x * blockDim.x + threadIdx.x;
    if (t >= n) return;
    float rx, ry, rz;
    atom_rel(cell, pos, t, &rx, &ry, &rz);
    int p = atomicAdd(&cursor[bin_of(rx, ry, rz)], 1);
    sorted[p] = make_float4(rx, ry, rz, q[t]);
    sortedIdx[p] = t;
}

// ---------- oct scatter: thread owns 2x2x2 cells, register accumulators ----------
// No atomics, no LDS; speculative next-atom prefetch; 262144 threads (4 waves/SIMD).

__global__ __launch_bounds__(256) void oct_scatter_kernel(const float4* __restrict__ atoms,
                                                          const int* __restrict__ offsets,
                                                          float* __restrict__ rmesh) {
    const int tid = blockIdx.x * 256 + threadIdx.x;   // 262144 threads
    const int zq = tid & 63;                          // z in low bits: wave shares xy bins
    const int gy = (tid >> 6) & 63;
    const int gx = tid >> 12;
    const int cx0 = gx << 1, cy0 = gy << 1, cz0 = zq << 1;

    float a000 = 0.0f, a001 = 0.0f, a010 = 0.0f, a011 = 0.0f;
    float a100 = 0.0f, a101 = 0.0f, a110 = 0.0f, a111 = 0.0f;   // [x][y][z]

    const float fcx = (float)cx0, fcy = (float)cy0, fcz = (float)cz0;

    // x cells [cx0-2, cx0+2] -> 3 bins (1 slop cell); y same; z cells [cz0-2, cz0+3] -> exactly 3 bins
    const int xb0 = ((cx0 - 2) & 127) >> 1;
    const int yb0 = ((cy0 - 2) & 127) >> 1;
    const int zb0 = ((cz0 - 2) & 127) >> 1;
    int len0 = 64 - zb0; if (len0 > 3) len0 = 3;
    const int len1 = 3 - len0;

    // flat ranges: r in [0,18): xy = r>>1 (dx=xy/3, dy=xy%3), half = r&1
    int r = -1, i = 0, e = 0;
    while (i >= e) {
        if (++r >= 18) break;
        int half = r & 1;
        if (half == 1 && len1 == 0) continue;
        int xy = r >> 1;
        int dx = xy / 3, dy = xy - dx * 3;
        int bx = (xb0 + dx) & 63;
        int by = (yb0 + dy) & 63;
        int binBase = ((bx << 6) | by) << 6;
        if (half == 0) { i = offsets[binBase + zb0]; e = offsets[binBase + zb0 + len0]; }
        else           { i = offsets[binBase];       e = offsets[binBase + len1]; }
    }

    if (r < 18) {
        float4 a = atoms[i];
        for (;;) {
            // speculative prefetch of the next atom in this range (dup if at end)
            float4 aspec = atoms[(i + 1 < e) ? (i + 1) : i];

            float ux = wrap128(a.x - fcx);
            float wx0 = bspline(ux);
            float wx1 = bspline(ux - 1.0f);
            float uy = wrap128(a.y - fcy);
            float wy0 = bspline(uy);
            float wy1 = bspline(uy - 1.0f);
            float uz = wrap128(a.z - fcz);
            float wz0 = bspline(uz);
            float wz1 = bspline(uz - 1.0f);
            float qs = a.w * (1.0f / 216.0f);
            float qx0 = qs * wx0, qx1 = qs * wx1;
            float m00 = qx0 * wy0, m01 = qx0 * wy1;
            float m10 = qx1 * wy0, m11 = qx1 * wy1;
            a000 += m00 * wz0; a001 += m00 * wz1;
            a010 += m01 * wz0; a011 += m01 * wz1;
            a100 += m10 * wz0; a101 += m10 * wz1;
            a110 += m11 * wz0; a111 += m11 * wz1;

            ++i;
            if (i < e) {
                a = aspec;
            } else {
                while (i >= e) {
                    if (++r >= 18) break;
                    int half = r & 1;
                    if (half == 1 && len1 == 0) continue;
                    int xy = r >> 1;
                    int dx = xy / 3, dy = xy - dx * 3;
                    int bx = (xb0 + dx) & 63;
                    int by = (yb0 + dy) & 63;
                    int binBase = ((bx << 6) | by) << 6;
                    if (half == 0) { i = offsets[binBase + zb0]; e = offsets[binBase + zb0 + len0]; }
                    else           { i = offsets[binBase];       e = offsets[binBase + len1]; }
                }
                if (r >= 18) break;
                a = atoms[i];
            }
        }
    }

    // coalesced float2 stores (lane = z-chunk -> consecutive 8B)
    *(float2*)&rmesh[((size_t)cx0       << 14) | ((size_t)cy0       << 7) | (size_t)cz0] = make_float2(a000, a001);
    *(float2*)&rmesh[((size_t)cx0       << 14) | ((size_t)(cy0 + 1) << 7) | (size_t)cz0] = make_float2(a010, a011);
    *(float2*)&rmesh[((size_t)(cx0 + 1) << 14) | ((size_t)cy0       << 7) | (size_t)cz0] = make_float2(a100, a101);
    *(float2*)&rmesh[((size_t)(cx0 + 1) << 14) | ((size_t)(cy0 + 1) << 7) | (size_t)cz0] = make_float2(a110, a111);
}

// ---------- register-shuffle 128-pt FFT (wave per line) ----------

__device__ inline void bfly_dif(float& rr, float& ii, int h, bool hi, float cs, float sn) {
    float pr = __shfl_xor(rr, h), pi = __shfl_xor(ii, h);
    float br = hi ? (pr - rr) : (rr + pr);
    float bi = hi ? (pi - ii) : (ii + pi);
    rr = cs * br - sn * bi;
    ii = cs * bi + sn * br;
}

__device__ inline void bfly_dit(float& rr, float& ii, int h, bool hi, float cs, float sn) {
    float pr = __shfl_xor(rr, h), pi = __shfl_xor(ii, h);
    float xr = hi ? rr : pr, xi = hi ? ii : pi;
    float br = hi ? pr : rr, bi = hi ? pi : ii;
    float tr = cs * xr - sn * xi, ti = cs * xi + sn * xr;
    rr = hi ? (br - tr) : (br + tr);
    ii = hi ? (bi - ti) : (bi + ti);
}

__device__ inline void wfft_dif_fwd(float& r0, float& i0, float& r1, float& i1, int lane) {
    {
        float ang = -PI_F * (float)lane * (1.0f / 64.0f);
        float sn, cs; __sincosf(ang, &sn, &cs);
        float ar = r0 + r1, ai = i0 + i1;
        float dr = r0 - r1, di = i0 - i1;
        r0 = ar; i0 = ai;
        r1 = cs * dr - sn * di;
        i1 = cs * di + sn * dr;
    }
    #pragma unroll
    for (int h = 32; h >= 1; h >>= 1) {
        int pos = lane & (h - 1);
        bool hi = (lane & h) != 0;
        float ang = hi ? (-PI_F * (float)pos / (float)h) : 0.0f;
        float sn, cs; __sincosf(ang, &sn, &cs);
        bfly_dif(r0, i0, h, hi, cs, sn);
        bfly_dif(r1, i1, h, hi, cs, sn);
    }
}

__device__ inline void wfft_dit_inv(float& r0, float& i0, float& r1, float& i1, int lane) {
    #pragma unroll
    for (int h = 1; h <= 32; h <<= 1) {
        int pos = lane & (h - 1);
        bool hi = (lane & h) != 0;
        float ang = PI_F * (float)pos / (float)h;
        float sn, cs; __sincosf(ang, &sn, &cs);
        bfly_dit(r0, i0, h, hi, cs, sn);
        bfly_dit(r1, i1, h, hi, cs, sn);
    }
    {
        float ang = PI_F * (float)lane * (1.0f / 64.0f);
        float sn, cs; __sincosf(ang, &sn, &cs);
        float tr = cs * r1 - sn * i1, ti = cs * i1 + sn * r1;
        float nr = r0 + tr, ni = i0 + ti;
        r1 = r0 - tr; i1 = i0 - ti;
        r0 = nr; i0 = ni;
    }
}

// ---------- z forward: real -> complex natural order (Hermitian prefix) ----------

__global__ __launch_bounds__(1024) void fftZfwd(const float* __restrict__ rin,
                                                float2* __restrict__ mesh) {
    __shared__ float tre[16][132], tim[16][132];
    const int t = threadIdx.x, b = blockIdx.x;
    for (int u = t; u < 2048; u += 1024) {
        int l = u >> 7, e = u & 127;
        tre[l][e] = rin[((size_t)((b << 4) | l) << 7) + e];
    }
    __syncthreads();
    const int w = t >> 6, lane = t & 63;
    float r0 = tre[w][lane],      i0 = 0.0f;
    float r1 = tre[w][lane + 64], i1 = 0.0f;
    wfft_dif_fwd(r0, i0, r1, i1, lane);
    int e0 = (int)(__brev((unsigned)lane) >> 25);
    tre[w][e0] = r0;     tim[w][e0] = i0;
    tre[w][e0 + 1] = r1; tim[w][e0 + 1] = i1;
    __syncthreads();
    for (int u = t; u < 2048; u += 1024) {
        int l = u >> 7, e = u & 127;
        if (e < ZP)
            mesh[(size_t)((b << 4) | l) * ZP + e] = make_float2(tre[l][e], tim[l][e]);
    }
}

// ---------- y forward: natural in -> bit-reversed positions ----------

__global__ __launch_bounds__(512) void fftYfwd(float2* __restrict__ mesh) {
    __shared__ float tre[8][132], tim[8][132];
    const int t = threadIdx.x, b = blockIdx.x;
    const int x = b & 127, zf0 = (b >> 7) << 3;
    const size_t rb = ((size_t)(x << 7)) * ZP + zf0;
    for (int u = t; u < 1024; u += 512) {
        int e = u >> 3, dz = u & 7;
        float2 vv = mesh[rb + (size_t)e * ZP + dz];
        tre[dz][e] = vv.x; tim[dz][e] = vv.y;
    }
    __syncthreads();
    const int w = t >> 6, lane = t & 63;
    float r0 = tre[w][lane],      i0 = tim[w][lane];
    float r1 = tre[w][lane + 64], i1 = tim[w][lane + 64];
    wfft_dif_fwd(r0, i0, r1, i1, lane);
    tre[w][lane] = r0;      tim[w][lane] = i0;
    tre[w][lane + 64] = r1; tim[w][lane + 64] = i1;
    __syncthreads();
    for (int u = t; u < 1024; u += 512) {
        int e = u >> 3, dz = u & 7;
        mesh[rb + (size_t)e * ZP + dz] = make_float2(tre[dz][e], tim[dz][e]);
    }
}

// ---------- fused x: DIF fwd -> G(k) at rev-indexed k -> DIT inv ----------

__global__ __launch_bounds__(512) void fftXGw(float2* __restrict__ mesh,
                                              const float* __restrict__ cell) {
    __shared__ float tre[8][132], tim[8][132];
    const int t = threadIdx.x, b = blockIdx.x;
    const int py = b & 127, zf0 = (b >> 7) << 3;
    for (int u = t; u < 1024; u += 512) {
        int e = u >> 3, dz = u & 7;
        float2 vv = mesh[(size_t)((e << 7) | py) * ZP + zf0 + dz];
        tre[dz][e] = vv.x; tim[dz][e] = vv.y;
    }
    __syncthreads();
    const int w = t >> 6, lane = t & 63;
    float r0 = tre[w][lane],      i0 = tim[w][lane];
    float r1 = tre[w][lane + 64], i1 = tim[w][lane + 64];
    wfft_dif_fwd(r0, i0, r1, i1, lane);
    {
        float inv[9]; float det; inv3x3(cell, inv, &det);
        float invVol = 1.0f / fabsf(det);
        int my = (int)(__brev((unsigned)py) >> 25);
        int mz = zf0 + w;
        float fy = (my < 64) ? (float)my : (float)(my - 128);
        float fz = (mz < 64) ? (float)mz : (float)(mz - 128);
        int mx0 = (int)(__brev((unsigned)lane) >> 25);
        #pragma unroll
        for (int s = 0; s < 2; ++s) {
            int mx = mx0 + s;
            float fx = (mx < 64) ? (float)mx : (float)(mx - 128);
            float kx = TWO_PI_F * (fx * inv[0] + fy * inv[1] + fz * inv[2]);
            float ky = TWO_PI_F * (fx * inv[3] + fy * inv[4] + fz * inv[5]);
            float kz = TWO_PI_F * (fx * inv[6] + fy * inv[7] + fz * inv[8]);
            float ksq = kx * kx + ky * ky + kz * kz;
            float G = (ksq == 0.0f) ? 0.0f
                      : FOUR_PI_F / ksq * __expf(-0.5f * ksq) * invVol;
            if (s == 0) { r0 *= G; i0 *= G; } else { r1 *= G; i1 *= G; }
        }
    }
    wfft_dit_inv(r0, i0, r1, i1, lane);
    tre[w][lane] = r0;      tim[w][lane] = i0;
    tre[w][lane + 64] = r1; tim[w][lane + 64] = i1;
    __syncthreads();
    for (int u = t; u < 1024; u += 512) {
        int e = u >> 3, dz = u & 7;
        mesh[(size_t)((e << 7) | py) * ZP + zf0 + dz] =
            make_float2(tre[dz][e], tim[dz][e]);
    }
}

// ---------- y inverse: bit-reversed positions in -> natural out ----------

__global__ __launch_bounds__(512) void fftYinv(float2* __restrict__ mesh) {
    __shared__ float tre[8][132], tim[8][132];
    const int t = threadIdx.x, b = blockIdx.x;
    const int x = b & 127, zf0 = (b >> 7) << 3;
    const size_t rb = ((size_t)(x << 7)) * ZP + zf0;
    for (int u = t; u < 1024; u += 512) {
        int e = u >> 3, dz = u & 7;
        float2 vv = mesh[rb + (size_t)e * ZP + dz];
        tre[dz][e] = vv.x; tim[dz][e] = vv.y;
    }
    __syncthreads();
    const int w = t >> 6, lane = t & 63;
    float r0 = tre[w][lane],      i0 = tim[w][lane];
    float r1 = tre[w][lane + 64], i1 = tim[w][lane + 64];
    wfft_dit_inv(r0, i0, r1, i1, lane);
    tre[w][lane] = r0;      tim[w][lane] = i0;
    tre[w][lane + 64] = r1; tim[w][lane + 64] = i1;
    __syncthreads();
    for (int u = t; u < 1024; u += 512) {
        int e = u >> 3, dz = u & 7;
        mesh[rb + (size_t)e * ZP + dz] = make_float2(tre[dz][e], tim[dz][e]);
    }
}

// ---------- z inverse: Hermitian mirror -> real out ----------

__global__ __launch_bounds__(1024) void fftZinv(const float2* __restrict__ mesh,
                                                float* __restrict__ rout) {
    __shared__ float tre[16][132], tim[16][132];
    const int t = threadIdx.x, b = blockIdx.x;
    for (int u = t; u < 2048; u += 1024) {
        int l = u >> 7, e = u & 127;
        int src = (e <= 64) ? e : 128 - e;
        float2 vv = mesh[(size_t)((b << 4) | l) * ZP + src];
        tre[l][e] = vv.x;
        tim[l][e] = (e <= 64) ? vv.y : -vv.y;
    }
    __syncthreads();
    const int w = t >> 6, lane = t & 63;
    int e0 = (int)(__brev((unsigned)lane) >> 25);
    float r0 = tre[w][e0],     i0 = tim[w][e0];
    float r1 = tre[w][e0 + 1], i1 = tim[w][e0 + 1];
    wfft_dit_inv(r0, i0, r1, i1, lane);
    const size_t rb = ((size_t)((b << 4) | w) << 7);
    rout[rb + lane] = r0;
    rout[rb + lane + 64] = r1;
}

// ---------- gather ----------

__global__ void gather_kernel(const float4* __restrict__ sorted, const int* __restrict__ sortedIdx,
                              const float* __restrict__ rmesh, float* __restrict__ out, int n) {
    int t = blockIdx.x * blockDim.x + threadIdx.x;
    if (t >= n) return;
    float4 a = sorted[t];
    float wx[4], wy[4], wz[4];
    int ix[4], iy[4], iz[4];
    {
        float fl = floorf(a.x); int i0 = (int)fl; float x = a.x - fl - 0.5f; w4(x, wx);
        #pragma unroll
        for (int s = 0; s < 4; ++s) ix[s] = (i0 + s - 1) & 127;
    }
    {
        float fl = floorf(a.y); int i0 = (int)fl; float x = a.y - fl - 0.5f; w4(x, wy);
        #pragma unroll
        for (int s = 0; s < 4; ++s) iy[s] = (i0 + s - 1) & 127;
    }
    {
        float fl = floorf(a.z); int i0 = (int)fl; float x = a.z - fl - 0.5f; w4(x, wz);
        #pragma unroll
        for (int s = 0; s < 4; ++s) iz[s] = (i0 + s - 1) & 127;
    }
    float sum = 0.0f;
    #pragma unroll
    for (int i = 0; i < 4; ++i) {
        int bx = ix[i] << 14;
        float acc_i = 0.0f;
        #pragma unroll
        for (int j = 0; j < 4; ++j) {
            int bxy = bx | (iy[j] << 7);
            float acc_j = 0.0f;
            #pragma unroll
            for (int k = 0; k < 4; ++k) {
                acc_j += wz[k] * rmesh[bxy | iz[k]];
            }
            acc_i += wy[j] * acc_j;
        }
        sum += wx[i] * acc_i;
    }
    out[sortedIdx[t]] = sum - a.w * 0.79788456080286535588f;
}

// ---------- launch ----------

extern "C" void kernel_launch(void* const* d_in, const int* in_sizes, int n_in,
                              void* d_out, int out_size, void* d_ws, size_t ws_size,
                              hipStream_t stream) {
    const float* cell = (const float*)d_in[0];
    const float* pos  = (const float*)d_in[1];
    const float* q    = (const float*)d_in[2];
    float* out = (float*)d_out;
    const int n = in_sizes[2];

    char* ws = (char*)d_ws;
    size_t o = 0;
    float4* sorted   = (float4*)(ws + o); o += (size_t)n * 16;
    int* sortedIdx   = (int*)(ws + o);    o += (size_t)n * 4;  o = (o + 255) & ~(size_t)255;
    int* hist        = (int*)(ws + o);    o += (size_t)BINS * 4;            // also reorder cursor
    int* offsets     = (int*)(ws + o);    o += (size_t)(BINS + 4) * 4;
    int* partials    = (int*)(ws + o);    o += (size_t)SCAN_BLOCKS * 4; o = (o + 255) & ~(size_t)255;
    float2* mesh     = (float2*)(ws + o); o += (size_t)128 * 128 * ZP * 8;  // 9.4 MB
    float* rmesh     = (float*)(ws + o);  // NTOT * 4 = 8 MB

    zero_int_kernel<<<BINS / 256, 256, 0, stream>>>(hist, BINS);
    hist_kernel<<<(n + 255) / 256, 256, 0, stream>>>(cell, pos, hist, n);
    scan_local<<<SCAN_BLOCKS, 256, 0, stream>>>((const int4*)hist, (int4*)offsets, partials);
    scan_add<<<SCAN_BLOCKS, 256, 0, stream>>>((int4*)hist, (int4*)offsets, partials, offsets);
    reorder_kernel<<<(n + 255) / 256, 256, 0, stream>>>(cell, pos, q, hist, sorted, sortedIdx, n);

    oct_scatter_kernel<<<1024, 256, 0, stream>>>(sorted, offsets, rmesh);

    fftZfwd<<<1024, 1024, 0, stream>>>(rmesh, mesh);
    fftYfwd<<<9 * 128, 512, 0, stream>>>(mesh);
    fftXGw<<<9 * 128, 512, 0, stream>>>(mesh, cell);
    fftYinv<<<9 * 128, 512, 0, stream>>>(mesh);
    fftZinv<<<1024, 1024, 0, stream>>>(mesh, rmesh);

    gather_kernel<<<(n + 255) / 256, 256, 0, stream>>>(sorted, sortedIdx, rmesh, out, n);
}

// Round 12
// 141.156 us; speedup vs baseline: 1.1653x; 1.1653x over previous
//
#include <hip/hip_runtime.h>
#include <math.h>

#define NTOT (128*128*128)
#define NBIN2 64                 // bins per axis (2 cells per bin)
#define BINS (NBIN2*NBIN2*NBIN2) // 262144
#define SCAN_BLOCKS 256

#define ZP 72                    // complex-mesh z pitch (>= 65, mult of 8)
#define CAP 1024                 // staged atoms per scatter block (mean 763, +9.5 sigma)

#define PI_F      3.14159265358979323846f
#define TWO_PI_F  6.28318530717958647692f
#define FOUR_PI_F 12.5663706143591729539f

// ---------- helpers ----------

__device__ inline void inv3x3(const float* __restrict__ c, float* inv, float* detOut) {
    float a = c[0], b = c[1], cc = c[2];
    float d = c[3], e = c[4], f  = c[5];
    float g = c[6], h = c[7], i  = c[8];
    float A = e * i - f * h;
    float B = f * g - d * i;
    float C = d * h - e * g;
    float det = a * A + b * B + cc * C;
    float r = 1.0f / det;
    inv[0] = A * r;              inv[1] = (cc * h - b * i) * r;  inv[2] = (b * f - cc * e) * r;
    inv[3] = B * r;              inv[4] = (a * i - cc * g) * r;  inv[5] = (cc * d - a * f) * r;
    inv[6] = C * r;              inv[7] = (b * g - a * h) * r;   inv[8] = (a * e - b * d) * r;
    *detOut = det;
}

__device__ inline void w4(float x, float* w) {
    float x2 = x * x, x3 = x2 * x;
    w[0] = (1.0f  - 6.0f  * x + 12.0f * x2 - 8.0f  * x3) * (1.0f / 48.0f);
    w[1] = (23.0f - 30.0f * x - 12.0f * x2 + 24.0f * x3) * (1.0f / 48.0f);
    w[2] = (23.0f + 30.0f * x - 12.0f * x2 - 24.0f * x3) * (1.0f / 48.0f);
    w[3] = (1.0f  + 6.0f  * x + 12.0f * x2 + 8.0f  * x3) * (1.0f / 48.0f);
}

__device__ inline void atom_rel(const float* __restrict__ cell,
                                const float* __restrict__ pos, int t,
                                float* rx, float* ry, float* rz) {
    float inv[9]; float det;
    inv3x3(cell, inv, &det);
    float px = pos[3 * t], py = pos[3 * t + 1], pz = pos[3 * t + 2];
    *rx = (px * inv[0] + py * inv[3] + pz * inv[6]) * 128.0f;
    *ry = (px * inv[1] + py * inv[4] + pz * inv[7]) * 128.0f;
    *rz = (px * inv[2] + py * inv[5] + pz * inv[8]) * 128.0f;
}

__device__ inline int bin_of(float rx, float ry, float rz) {
    int ix = ((int)floorf(rx)) & 127;
    int iy = ((int)floorf(ry)) & 127;
    int iz = ((int)floorf(rz)) & 127;
    return ((((ix >> 1) << 6) | (iy >> 1)) << 6) | (iz >> 1);
}

// periodic wrap of a cell-units offset into (-64, 64]
__device__ inline float wrap128(float u) {
    u = (u > 64.0f) ? u - 128.0f : u;
    u = (u < -64.0f) ? u + 128.0f : u;
    return u;
}

// cubic B-spline M4 assignment weight (unnormalized: true weight = this / 6)
__device__ inline float bspline(float u) {
    float a = fabsf(u);
    float t = fmaxf(2.0f - a, 0.0f);
    float s = fmaxf(1.0f - a, 0.0f);
    return t * t * t - 4.0f * s * s * s;
}

// ---------- binning ----------

__global__ void zero_int_kernel(int* __restrict__ p, int n) {
    int i = blockIdx.x * blockDim.x + threadIdx.x;
    if (i < n) p[i] = 0;
}

__global__ void hist_kernel(const float* __restrict__ cell, const float* __restrict__ pos,
                            int* __restrict__ hist, int n) {
    int t = blockIdx.x * blockDim.x + threadIdx.x;
    if (t >= n) return;
    float rx, ry, rz;
    atom_rel(cell, pos, t, &rx, &ry, &rz);
    atomicAdd(&hist[bin_of(rx, ry, rz)], 1);
}

__global__ __launch_bounds__(256) void scan_local(const int4* __restrict__ hist4,
                                                  int4* __restrict__ off4,
                                                  int* __restrict__ partials) {
    const int b = blockIdx.x, t = threadIdx.x;
    const int idx = b * 256 + t;
    int4 h = hist4[idx];
    int s = h.x + h.y + h.z + h.w;
    int lane = t & 63, wv = t >> 6;
    int v = s;
    #pragma unroll
    for (int d = 1; d < 64; d <<= 1) {
        int o = __shfl_up(v, d, 64);
        if (lane >= d) v += o;
    }
    __shared__ int wsum[4];
    if (lane == 63) wsum[wv] = v;
    __syncthreads();
    int add = 0;
    #pragma unroll
    for (int k = 0; k < 4; ++k) if (k < wv) add += wsum[k];
    int run = add + v - s;
    int4 o4;
    o4.x = run; run += h.x;
    o4.y = run; run += h.y;
    o4.z = run; run += h.z;
    o4.w = run; run += h.w;
    off4[idx] = o4;
    if (t == 255) partials[b] = run;
}

__global__ __launch_bounds__(256) void scan_add(int4* __restrict__ hist4,
                                                int4* __restrict__ off4,
                                                const int* __restrict__ partials,
                                                int* __restrict__ offsets) {
    const int b = blockIdx.x, t = threadIdx.x;
    int lane = t & 63, wv = t >> 6;
    int v = (t < b) ? partials[t] : 0;
    #pragma unroll
    for (int d = 32; d >= 1; d >>= 1) v += __shfl_xor(v, d, 64);
    __shared__ int ws2[4];
    __shared__ int base_s;
    if (lane == 0) ws2[wv] = v;
    __syncthreads();
    if (t == 0) base_s = ws2[0] + ws2[1] + ws2[2] + ws2[3];
    __syncthreads();
    const int base = base_s;
    const int idx = b * 256 + t;
    int4 o4 = off4[idx];
    o4.x += base; o4.y += base; o4.z += base; o4.w += base;
    off4[idx]  = o4;
    hist4[idx] = o4;
    if (b == SCAN_BLOCKS - 1 && t == 255) offsets[BINS] = base + partials[b];
}

__global__ void reorder_kernel(const float* __restrict__ cell, const float* __restrict__ pos,
                               const float* __restrict__ q, int* __restrict__ cursor,
                               float4* __restrict__ sorted, int* __restrict__ sortedIdx, int n) {
    int t = blockIdx.x * blockDim.x + threadIdx.x;
    if (t >= n) return;
    float rx, ry, rz;
    atom_rel(cell, pos, t, &rx, &ry, &rz);
    int p = atomicAdd(&cursor[bin_of(rx, ry, rz)], 1);
    sorted[p] = make_float4(rx, ry, rz, q[t]);
    sortedIdx[p] = t;
}

// ---------- LDS-staged oct scatter ----------
// Block = 16x16x16 cells (512 blocks, 2/CU). Stage the 10x10x10-bin atom
// neighborhood into LDS in one parallel pass; each thread then accumulates
// its 2x2x2 cells from LDS (fast range bounds + atom loads). No atomics.

__global__ __launch_bounds__(512) void lds_scatter_kernel(const float4* __restrict__ atoms,
                                                          const int* __restrict__ offsets,
                                                          float* __restrict__ rmesh) {
    const int blk = blockIdx.x;                 // 8x8x8 blocks
    const int bz = blk & 7, by = (blk >> 3) & 7, bx = blk >> 6;
    const int ox = bx << 4, oy = by << 4, oz = bz << 4;
    const int gbx0 = ((ox - 2) & 127) >> 1;     // staged-bin origin (global bin coords)
    const int gby0 = ((oy - 2) & 127) >> 1;
    const int gbz0 = ((oz - 2) & 127) >> 1;

    __shared__ float4 satoms[CAP];              // 16 KB
    __shared__ int P[1025];                     // staged-bin prefix (local)
    __shared__ int wsum[8];

    const int t = threadIdx.x;

    // --- counts + global starts for staged bins 2t, 2t+1 (b = (jx*10+jy)*10+jz) ---
    int c0 = 0, c1 = 0, g0 = 0, g1 = 0;
    {
        int b = 2 * t;
        if (b < 1000) {
            int jx = b / 100, rr = b - jx * 100, jy = rr / 10, jz = rr - jy * 10;
            int gb = ((((gbx0 + jx) & 63) << 6) | ((gby0 + jy) & 63)) << 6 | ((gbz0 + jz) & 63);
            g0 = offsets[gb]; c0 = offsets[gb + 1] - g0;
        }
        b = 2 * t + 1;
        if (b < 1000) {
            int jx = b / 100, rr = b - jx * 100, jy = rr / 10, jz = rr - jy * 10;
            int gb = ((((gbx0 + jx) & 63) << 6) | ((gby0 + jy) & 63)) << 6 | ((gbz0 + jz) & 63);
            g1 = offsets[gb]; c1 = offsets[gb + 1] - g1;
        }
    }

    // --- block-wide exclusive scan over 512 thread-sums ---
    int s = c0 + c1;
    int lane = t & 63, wv = t >> 6;
    int v = s;
    #pragma unroll
    for (int d = 1; d < 64; d <<= 1) {
        int o = __shfl_up(v, d, 64);
        if (lane >= d) v += o;
    }
    if (lane == 63) wsum[wv] = v;
    __syncthreads();
    int add = 0;
    #pragma unroll
    for (int k = 0; k < 8; ++k) if (k < wv) add += wsum[k];
    const int pre = add + v - s;
    P[2 * t] = pre;
    P[2 * t + 1] = pre + c0;
    if (t == 511) P[1024] = add + v;
    __syncthreads();

    // --- staging copy (parallel across threads; ~1.5 atoms each) ---
    for (int k = 0; k < c0; ++k) {
        int d = pre + k;
        if (d >= CAP) break;
        satoms[d] = atoms[g0 + k];
    }
    {
        int pre1 = pre + c0;
        for (int k = 0; k < c1; ++k) {
            int d = pre1 + k;
            if (d >= CAP) break;
            satoms[d] = atoms[g1 + k];
        }
    }
    __syncthreads();

    // --- consumption: thread owns 2x2x2 cells ---
    const int qz = t & 7, qy = (t >> 3) & 7, qx = t >> 6;
    const int cx0 = ox + (qx << 1), cy0 = oy + (qy << 1), cz0 = oz + (qz << 1);
    const float fcx = (float)cx0, fcy = (float)cy0, fcz = (float)cz0;

    float a000 = 0.0f, a001 = 0.0f, a010 = 0.0f, a011 = 0.0f;
    float a100 = 0.0f, a101 = 0.0f, a110 = 0.0f, a111 = 0.0f;   // [x][y][z]

    // flat iterator over 9 xy sub-bins; z-triple contiguous in P (bin = xy*10 + jz)
    int r = -1, i = 0, e = 0;
    while (i >= e) {
        if (++r >= 9) break;
        int dbx = r / 3, dby = r - dbx * 3;
        int bin0 = ((qx + dbx) * 10 + (qy + dby)) * 10 + qz;
        i = P[bin0];
        e = P[bin0 + 3];
        if (e > CAP) e = CAP;
    }
    while (r < 9) {
        float4 a = satoms[i];

        float ux = wrap128(a.x - fcx);
        float wx0 = bspline(ux);
        float wx1 = bspline(ux - 1.0f);
        float uy = wrap128(a.y - fcy);
        float wy0 = bspline(uy);
        float wy1 = bspline(uy - 1.0f);
        float uz = wrap128(a.z - fcz);
        float wz0 = bspline(uz);
        float wz1 = bspline(uz - 1.0f);
        float qs = a.w * (1.0f / 216.0f);
        float qx0 = qs * wx0, qx1 = qs * wx1;
        float m00 = qx0 * wy0, m01 = qx0 * wy1;
        float m10 = qx1 * wy0, m11 = qx1 * wy1;
        a000 += m00 * wz0; a001 += m00 * wz1;
        a010 += m01 * wz0; a011 += m01 * wz1;
        a100 += m10 * wz0; a101 += m10 * wz1;
        a110 += m11 * wz0; a111 += m11 * wz1;

        if (++i >= e) {
            while (i >= e) {
                if (++r >= 9) break;
                int dbx = r / 3, dby = r - dbx * 3;
                int bin0 = ((qx + dbx) * 10 + (qy + dby)) * 10 + qz;
                i = P[bin0];
                e = P[bin0 + 3];
                if (e > CAP) e = CAP;
            }
            if (r >= 9) break;
        }
    }

    *(float2*)&rmesh[((size_t)cx0       << 14) | ((size_t)cy0       << 7) | (size_t)cz0] = make_float2(a000, a001);
    *(float2*)&rmesh[((size_t)cx0       << 14) | ((size_t)(cy0 + 1) << 7) | (size_t)cz0] = make_float2(a010, a011);
    *(float2*)&rmesh[((size_t)(cx0 + 1) << 14) | ((size_t)cy0       << 7) | (size_t)cz0] = make_float2(a100, a101);
    *(float2*)&rmesh[((size_t)(cx0 + 1) << 14) | ((size_t)(cy0 + 1) << 7) | (size_t)cz0] = make_float2(a110, a111);
}

// ---------- register-shuffle 128-pt FFT (wave per line) ----------

__device__ inline void bfly_dif(float& rr, float& ii, int h, bool hi, float cs, float sn) {
    float pr = __shfl_xor(rr, h), pi = __shfl_xor(ii, h);
    float br = hi ? (pr - rr) : (rr + pr);
    float bi = hi ? (pi - ii) : (ii + pi);
    rr = cs * br - sn * bi;
    ii = cs * bi + sn * br;
}

__device__ inline void bfly_dit(float& rr, float& ii, int h, bool hi, float cs, float sn) {
    float pr = __shfl_xor(rr, h), pi = __shfl_xor(ii, h);
    float xr = hi ? rr : pr, xi = hi ? ii : pi;
    float br = hi ? pr : rr, bi = hi ? pi : ii;
    float tr = cs * xr - sn * xi, ti = cs * xi + sn * xr;
    rr = hi ? (br - tr) : (br + tr);
    ii = hi ? (bi - ti) : (bi + ti);
}

__device__ inline void wfft_dif_fwd(float& r0, float& i0, float& r1, float& i1, int lane) {
    {
        float ang = -PI_F * (float)lane * (1.0f / 64.0f);
        float sn, cs; __sincosf(ang, &sn, &cs);
        float ar = r0 + r1, ai = i0 + i1;
        float dr = r0 - r1, di = i0 - i1;
        r0 = ar; i0 = ai;
        r1 = cs * dr - sn * di;
        i1 = cs * di + sn * dr;
    }
    #pragma unroll
    for (int h = 32; h >= 1; h >>= 1) {
        int pos = lane & (h - 1);
        bool hi = (lane & h) != 0;
        float ang = hi ? (-PI_F * (float)pos / (float)h) : 0.0f;
        float sn, cs; __sincosf(ang, &sn, &cs);
        bfly_dif(r0, i0, h, hi, cs, sn);
        bfly_dif(r1, i1, h, hi, cs, sn);
    }
}

__device__ inline void wfft_dit_inv(float& r0, float& i0, float& r1, float& i1, int lane) {
    #pragma unroll
    for (int h = 1; h <= 32; h <<= 1) {
        int pos = lane & (h - 1);
        bool hi = (lane & h) != 0;
        float ang = PI_F * (float)pos / (float)h;
        float sn, cs; __sincosf(ang, &sn, &cs);
        bfly_dit(r0, i0, h, hi, cs, sn);
        bfly_dit(r1, i1, h, hi, cs, sn);
    }
    {
        float ang = PI_F * (float)lane * (1.0f / 64.0f);
        float sn, cs; __sincosf(ang, &sn, &cs);
        float tr = cs * r1 - sn * i1, ti = cs * i1 + sn * r1;
        float nr = r0 + tr, ni = i0 + ti;
        r1 = r0 - tr; i1 = i0 - ti;
        r0 = nr; i0 = ni;
    }
}

// ---------- z forward: real -> complex natural order (Hermitian prefix) ----------

__global__ __launch_bounds__(1024) void fftZfwd(const float* __restrict__ rin,
                                                float2* __restrict__ mesh) {
    __shared__ float tre[16][132], tim[16][132];
    const int t = threadIdx.x, b = blockIdx.x;
    for (int u = t; u < 2048; u += 1024) {
        int l = u >> 7, e = u & 127;
        tre[l][e] = rin[((size_t)((b << 4) | l) << 7) + e];
    }
    __syncthreads();
    const int w = t >> 6, lane = t & 63;
    float r0 = tre[w][lane],      i0 = 0.0f;
    float r1 = tre[w][lane + 64], i1 = 0.0f;
    wfft_dif_fwd(r0, i0, r1, i1, lane);
    int e0 = (int)(__brev((unsigned)lane) >> 25);
    tre[w][e0] = r0;     tim[w][e0] = i0;
    tre[w][e0 + 1] = r1; tim[w][e0 + 1] = i1;
    __syncthreads();
    for (int u = t; u < 2048; u += 1024) {
        int l = u >> 7, e = u & 127;
        if (e < ZP)
            mesh[(size_t)((b << 4) | l) * ZP + e] = make_float2(tre[l][e], tim[l][e]);
    }
}

// ---------- y forward: natural in -> bit-reversed positions ----------

__global__ __launch_bounds__(512) void fftYfwd(float2* __restrict__ mesh) {
    __shared__ float tre[8][132], tim[8][132];
    const int t = threadIdx.x, b = blockIdx.x;
    const int x = b & 127, zf0 = (b >> 7) << 3;
    const size_t rb = ((size_t)(x << 7)) * ZP + zf0;
    for (int u = t; u < 1024; u += 512) {
        int e = u >> 3, dz = u & 7;
        float2 vv = mesh[rb + (size_t)e * ZP + dz];
        tre[dz][e] = vv.x; tim[dz][e] = vv.y;
    }
    __syncthreads();
    const int w = t >> 6, lane = t & 63;
    float r0 = tre[w][lane],      i0 = tim[w][lane];
    float r1 = tre[w][lane + 64], i1 = tim[w][lane + 64];
    wfft_dif_fwd(r0, i0, r1, i1, lane);
    tre[w][lane] = r0;      tim[w][lane] = i0;
    tre[w][lane + 64] = r1; tim[w][lane + 64] = i1;
    __syncthreads();
    for (int u = t; u < 1024; u += 512) {
        int e = u >> 3, dz = u & 7;
        mesh[rb + (size_t)e * ZP + dz] = make_float2(tre[dz][e], tim[dz][e]);
    }
}

// ---------- fused x: DIF fwd -> G(k) at rev-indexed k -> DIT inv ----------

__global__ __launch_bounds__(512) void fftXGw(float2* __restrict__ mesh,
                                              const float* __restrict__ cell) {
    __shared__ float tre[8][132], tim[8][132];
    const int t = threadIdx.x, b = blockIdx.x;
    const int py = b & 127, zf0 = (b >> 7) << 3;
    for (int u = t; u < 1024; u += 512) {
        int e = u >> 3, dz = u & 7;
        float2 vv = mesh[(size_t)((e << 7) | py) * ZP + zf0 + dz];
        tre[dz][e] = vv.x; tim[dz][e] = vv.y;
    }
    __syncthreads();
    const int w = t >> 6, lane = t & 63;
    float r0 = tre[w][lane],      i0 = tim[w][lane];
    float r1 = tre[w][lane + 64], i1 = tim[w][lane + 64];
    wfft_dif_fwd(r0, i0, r1, i1, lane);
    {
        float inv[9]; float det; inv3x3(cell, inv, &det);
        float invVol = 1.0f / fabsf(det);
        int my = (int)(__brev((unsigned)py) >> 25);
        int mz = zf0 + w;
        float fy = (my < 64) ? (float)my : (float)(my - 128);
        float fz = (mz < 64) ? (float)mz : (float)(mz - 128);
        int mx0 = (int)(__brev((unsigned)lane) >> 25);
        #pragma unroll
        for (int s = 0; s < 2; ++s) {
            int mx = mx0 + s;
            float fx = (mx < 64) ? (float)mx : (float)(mx - 128);
            float kx = TWO_PI_F * (fx * inv[0] + fy * inv[1] + fz * inv[2]);
            float ky = TWO_PI_F * (fx * inv[3] + fy * inv[4] + fz * inv[5]);
            float kz = TWO_PI_F * (fx * inv[6] + fy * inv[7] + fz * inv[8]);
            float ksq = kx * kx + ky * ky + kz * kz;
            float G = (ksq == 0.0f) ? 0.0f
                      : FOUR_PI_F / ksq * __expf(-0.5f * ksq) * invVol;
            if (s == 0) { r0 *= G; i0 *= G; } else { r1 *= G; i1 *= G; }
        }
    }
    wfft_dit_inv(r0, i0, r1, i1, lane);
    tre[w][lane] = r0;      tim[w][lane] = i0;
    tre[w][lane + 64] = r1; tim[w][lane + 64] = i1;
    __syncthreads();
    for (int u = t; u < 1024; u += 512) {
        int e = u >> 3, dz = u & 7;
        mesh[(size_t)((e << 7) | py) * ZP + zf0 + dz] =
            make_float2(tre[dz][e], tim[dz][e]);
    }
}

// ---------- y inverse: bit-reversed positions in -> natural out ----------

__global__ __launch_bounds__(512) void fftYinv(float2* __restrict__ mesh) {
    __shared__ float tre[8][132], tim[8][132];
    const int t = threadIdx.x, b = blockIdx.x;
    const int x = b & 127, zf0 = (b >> 7) << 3;
    const size_t rb = ((size_t)(x << 7)) * ZP + zf0;
    for (int u = t; u < 1024; u += 512) {
        int e = u >> 3, dz = u & 7;
        float2 vv = mesh[rb + (size_t)e * ZP + dz];
        tre[dz][e] = vv.x; tim[dz][e] = vv.y;
    }
    __syncthreads();
    const int w = t >> 6, lane = t & 63;
    float r0 = tre[w][lane],      i0 = tim[w][lane];
    float r1 = tre[w][lane + 64], i1 = tim[w][lane + 64];
    wfft_dit_inv(r0, i0, r1, i1, lane);
    tre[w][lane] = r0;      tim[w][lane] = i0;
    tre[w][lane + 64] = r1; tim[w][lane + 64] = i1;
    __syncthreads();
    for (int u = t; u < 1024; u += 512) {
        int e = u >> 3, dz = u & 7;
        mesh[rb + (size_t)e * ZP + dz] = make_float2(tre[dz][e], tim[dz][e]);
    }
}

// ---------- z inverse: Hermitian mirror -> real out ----------

__global__ __launch_bounds__(1024) void fftZinv(const float2* __restrict__ mesh,
                                                float* __restrict__ rout) {
    __shared__ float tre[16][132], tim[16][132];
    const int t = threadIdx.x, b = blockIdx.x;
    for (int u = t; u < 2048; u += 1024) {
        int l = u >> 7, e = u & 127;
        int src = (e <= 64) ? e : 128 - e;
        float2 vv = mesh[(size_t)((b << 4) | l) * ZP + src];
        tre[l][e] = vv.x;
        tim[l][e] = (e <= 64) ? vv.y : -vv.y;
    }
    __syncthreads();
    const int w = t >> 6, lane = t & 63;
    int e0 = (int)(__brev((unsigned)lane) >> 25);
    float r0 = tre[w][e0],     i0 = tim[w][e0];
    float r1 = tre[w][e0 + 1], i1 = tim[w][e0 + 1];
    wfft_dit_inv(r0, i0, r1, i1, lane);
    const size_t rb = ((size_t)((b << 4) | w) << 7);
    rout[rb + lane] = r0;
    rout[rb + lane + 64] = r1;
}

// ---------- gather ----------

__global__ void gather_kernel(const float4* __restrict__ sorted, const int* __restrict__ sortedIdx,
                              const float* __restrict__ rmesh, float* __restrict__ out, int n) {
    int t = blockIdx.x * blockDim.x + threadIdx.x;
    if (t >= n) return;
    float4 a = sorted[t];
    float wx[4], wy[4], wz[4];
    int ix[4], iy[4], iz[4];
    {
        float fl = floorf(a.x); int i0 = (int)fl; float x = a.x - fl - 0.5f; w4(x, wx);
        #pragma unroll
        for (int s = 0; s < 4; ++s) ix[s] = (i0 + s - 1) & 127;
    }
    {
        float fl = floorf(a.y); int i0 = (int)fl; float x = a.y - fl - 0.5f; w4(x, wy);
        #pragma unroll
        for (int s = 0; s < 4; ++s) iy[s] = (i0 + s - 1) & 127;
    }
    {
        float fl = floorf(a.z); int i0 = (int)fl; float x = a.z - fl - 0.5f; w4(x, wz);
        #pragma unroll
        for (int s = 0; s < 4; ++s) iz[s] = (i0 + s - 1) & 127;
    }
    float sum = 0.0f;
    #pragma unroll
    for (int i = 0; i < 4; ++i) {
        int bx = ix[i] << 14;
        float acc_i = 0.0f;
        #pragma unroll
        for (int j = 0; j < 4; ++j) {
            int bxy = bx | (iy[j] << 7);
            float acc_j = 0.0f;
            #pragma unroll
            for (int k = 0; k < 4; ++k) {
                acc_j += wz[k] * rmesh[bxy | iz[k]];
            }
            acc_i += wy[j] * acc_j;
        }
        sum += wx[i] * acc_i;
    }
    out[sortedIdx[t]] = sum - a.w * 0.79788456080286535588f;
}

// ---------- launch ----------

extern "C" void kernel_launch(void* const* d_in, const int* in_sizes, int n_in,
                              void* d_out, int out_size, void* d_ws, size_t ws_size,
                              hipStream_t stream) {
    const float* cell = (const float*)d_in[0];
    const float* pos  = (const float*)d_in[1];
    const float* q    = (const float*)d_in[2];
    float* out = (float*)d_out;
    const int n = in_sizes[2];

    char* ws = (char*)d_ws;
    size_t o = 0;
    float4* sorted   = (float4*)(ws + o); o += (size_t)n * 16;
    int* sortedIdx   = (int*)(ws + o);    o += (size_t)n * 4;  o = (o + 255) & ~(size_t)255;
    int* hist        = (int*)(ws + o);    o += (size_t)BINS * 4;            // also reorder cursor
    int* offsets     = (int*)(ws + o);    o += (size_t)(BINS + 4) * 4;
    int* partials    = (int*)(ws + o);    o += (size_t)SCAN_BLOCKS * 4; o = (o + 255) & ~(size_t)255;
    float2* mesh     = (float2*)(ws + o); o += (size_t)128 * 128 * ZP * 8;  // 9.4 MB
    float* rmesh     = (float*)(ws + o);  // NTOT * 4 = 8 MB

    zero_int_kernel<<<BINS / 256, 256, 0, stream>>>(hist, BINS);
    hist_kernel<<<(n + 255) / 256, 256, 0, stream>>>(cell, pos, hist, n);
    scan_local<<<SCAN_BLOCKS, 256, 0, stream>>>((const int4*)hist, (int4*)offsets, partials);
    scan_add<<<SCAN_BLOCKS, 256, 0, stream>>>((int4*)hist, (int4*)offsets, partials, offsets);
    reorder_kernel<<<(n + 255) / 256, 256, 0, stream>>>(cell, pos, q, hist, sorted, sortedIdx, n);

    lds_scatter_kernel<<<512, 512, 0, stream>>>(sorted, offsets, rmesh);

    fftZfwd<<<1024, 1024, 0, stream>>>(rmesh, mesh);
    fftYfwd<<<9 * 128, 512, 0, stream>>>(mesh);
    fftXGw<<<9 * 128, 512, 0, stream>>>(mesh, cell);
    fftYinv<<<9 * 128, 512, 0, stream>>>(mesh);
    fftZinv<<<1024, 1024, 0, stream>>>(mesh, rmesh);

    gather_kernel<<<(n + 255) / 256, 256, 0, stream>>>(sorted, sortedIdx, rmesh, out, n);
}

// Round 13
// 135.746 us; speedup vs baseline: 1.2118x; 1.0399x over previous
//
#include <hip/hip_runtime.h>
#include <math.h>

#define NTOT (128*128*128)
#define NBIN2 64                 // bins per axis (2 cells per bin)
#define BINS (NBIN2*NBIN2*NBIN2) // 262144
#define SCAN_BLOCKS 256

#define ZP 72                    // complex-mesh z pitch (>= 65, mult of 8)
#define CAP 1024                 // staged atoms per scatter block (mean 763, +9.5 sigma)

#define PI_F      3.14159265358979323846f
#define TWO_PI_F  6.28318530717958647692f
#define FOUR_PI_F 12.5663706143591729539f

// ---------- helpers ----------

__device__ inline void inv3x3(const float* __restrict__ c, float* inv, float* detOut) {
    float a = c[0], b = c[1], cc = c[2];
    float d = c[3], e = c[4], f  = c[5];
    float g = c[6], h = c[7], i  = c[8];
    float A = e * i - f * h;
    float B = f * g - d * i;
    float C = d * h - e * g;
    float det = a * A + b * B + cc * C;
    float r = 1.0f / det;
    inv[0] = A * r;              inv[1] = (cc * h - b * i) * r;  inv[2] = (b * f - cc * e) * r;
    inv[3] = B * r;              inv[4] = (a * i - cc * g) * r;  inv[5] = (cc * d - a * f) * r;
    inv[6] = C * r;              inv[7] = (b * g - a * h) * r;   inv[8] = (a * e - b * d) * r;
    *detOut = det;
}

__device__ inline void atom_rel(const float* __restrict__ cell,
                                const float* __restrict__ pos, int t,
                                float* rx, float* ry, float* rz) {
    float inv[9]; float det;
    inv3x3(cell, inv, &det);
    float px = pos[3 * t], py = pos[3 * t + 1], pz = pos[3 * t + 2];
    *rx = (px * inv[0] + py * inv[3] + pz * inv[6]) * 128.0f;
    *ry = (px * inv[1] + py * inv[4] + pz * inv[7]) * 128.0f;
    *rz = (px * inv[2] + py * inv[5] + pz * inv[8]) * 128.0f;
}

__device__ inline int bin_of(float rx, float ry, float rz) {
    int ix = ((int)floorf(rx)) & 127;
    int iy = ((int)floorf(ry)) & 127;
    int iz = ((int)floorf(rz)) & 127;
    return ((((ix >> 1) << 6) | (iy >> 1)) << 6) | (iz >> 1);
}

// periodic wrap of a cell-units offset into (-64, 64]
__device__ inline float wrap128(float u) {
    u = (u > 64.0f) ? u - 128.0f : u;
    u = (u < -64.0f) ? u + 128.0f : u;
    return u;
}

// cubic B-spline M4 assignment weight (unnormalized: true weight = this / 6)
__device__ inline float bspline(float u) {
    float a = fabsf(u);
    float t = fmaxf(2.0f - a, 0.0f);
    float s = fmaxf(1.0f - a, 0.0f);
    return t * t * t - 4.0f * s * s * s;
}

// ---------- binning ----------

__global__ void zero_int_kernel(int* __restrict__ p, int n) {
    int i = blockIdx.x * blockDim.x + threadIdx.x;
    if (i < n) p[i] = 0;
}

__global__ void hist_kernel(const float* __restrict__ cell, const float* __restrict__ pos,
                            int* __restrict__ hist, int n) {
    int t = blockIdx.x * blockDim.x + threadIdx.x;
    if (t >= n) return;
    float rx, ry, rz;
    atom_rel(cell, pos, t, &rx, &ry, &rz);
    atomicAdd(&hist[bin_of(rx, ry, rz)], 1);
}

__global__ __launch_bounds__(256) void scan_local(const int4* __restrict__ hist4,
                                                  int4* __restrict__ off4,
                                                  int* __restrict__ partials) {
    const int b = blockIdx.x, t = threadIdx.x;
    const int idx = b * 256 + t;
    int4 h = hist4[idx];
    int s = h.x + h.y + h.z + h.w;
    int lane = t & 63, wv = t >> 6;
    int v = s;
    #pragma unroll
    for (int d = 1; d < 64; d <<= 1) {
        int o = __shfl_up(v, d, 64);
        if (lane >= d) v += o;
    }
    __shared__ int wsum[4];
    if (lane == 63) wsum[wv] = v;
    __syncthreads();
    int add = 0;
    #pragma unroll
    for (int k = 0; k < 4; ++k) if (k < wv) add += wsum[k];
    int run = add + v - s;
    int4 o4;
    o4.x = run; run += h.x;
    o4.y = run; run += h.y;
    o4.z = run; run += h.z;
    o4.w = run; run += h.w;
    off4[idx] = o4;
    if (t == 255) partials[b] = run;
}

__global__ __launch_bounds__(256) void scan_add(int4* __restrict__ hist4,
                                                int4* __restrict__ off4,
                                                const int* __restrict__ partials,
                                                int* __restrict__ offsets) {
    const int b = blockIdx.x, t = threadIdx.x;
    int lane = t & 63, wv = t >> 6;
    int v = (t < b) ? partials[t] : 0;
    #pragma unroll
    for (int d = 32; d >= 1; d >>= 1) v += __shfl_xor(v, d, 64);
    __shared__ int ws2[4];
    __shared__ int base_s;
    if (lane == 0) ws2[wv] = v;
    __syncthreads();
    if (t == 0) base_s = ws2[0] + ws2[1] + ws2[2] + ws2[3];
    __syncthreads();
    const int base = base_s;
    const int idx = b * 256 + t;
    int4 o4 = off4[idx];
    o4.x += base; o4.y += base; o4.z += base; o4.w += base;
    off4[idx]  = o4;
    hist4[idx] = o4;
    if (b == SCAN_BLOCKS - 1 && t == 255) offsets[BINS] = base + partials[b];
}

__global__ void reorder_kernel(const float* __restrict__ cell, const float* __restrict__ pos,
                               const float* __restrict__ q, int* __restrict__ cursor,
                               float4* __restrict__ sorted, int* __restrict__ sortedIdx, int n) {
    int t = blockIdx.x * blockDim.x + threadIdx.x;
    if (t >= n) return;
    float rx, ry, rz;
    atom_rel(cell, pos, t, &rx, &ry, &rz);
    int p = atomicAdd(&cursor[bin_of(rx, ry, rz)], 1);
    sorted[p] = make_float4(rx, ry, rz, q[t]);
    sortedIdx[p] = t;
}

// ---------- LDS-staged oct scatter (proven in round 12) ----------

__global__ __launch_bounds__(512) void lds_scatter_kernel(const float4* __restrict__ atoms,
                                                          const int* __restrict__ offsets,
                                                          float* __restrict__ rmesh) {
    const int blk = blockIdx.x;                 // 8x8x8 blocks
    const int bz = blk & 7, by = (blk >> 3) & 7, bx = blk >> 6;
    const int ox = bx << 4, oy = by << 4, oz = bz << 4;
    const int gbx0 = ((ox - 2) & 127) >> 1;
    const int gby0 = ((oy - 2) & 127) >> 1;
    const int gbz0 = ((oz - 2) & 127) >> 1;

    __shared__ float4 satoms[CAP];              // 16 KB
    __shared__ int P[1025];
    __shared__ int wsum[8];

    const int t = threadIdx.x;

    int c0 = 0, c1 = 0, g0 = 0, g1 = 0;
    {
        int b = 2 * t;
        if (b < 1000) {
            int jx = b / 100, rr = b - jx * 100, jy = rr / 10, jz = rr - jy * 10;
            int gb = ((((gbx0 + jx) & 63) << 6) | ((gby0 + jy) & 63)) << 6 | ((gbz0 + jz) & 63);
            g0 = offsets[gb]; c0 = offsets[gb + 1] - g0;
        }
        b = 2 * t + 1;
        if (b < 1000) {
            int jx = b / 100, rr = b - jx * 100, jy = rr / 10, jz = rr - jy * 10;
            int gb = ((((gbx0 + jx) & 63) << 6) | ((gby0 + jy) & 63)) << 6 | ((gbz0 + jz) & 63);
            g1 = offsets[gb]; c1 = offsets[gb + 1] - g1;
        }
    }

    int s = c0 + c1;
    int lane = t & 63, wv = t >> 6;
    int v = s;
    #pragma unroll
    for (int d = 1; d < 64; d <<= 1) {
        int o = __shfl_up(v, d, 64);
        if (lane >= d) v += o;
    }
    if (lane == 63) wsum[wv] = v;
    __syncthreads();
    int add = 0;
    #pragma unroll
    for (int k = 0; k < 8; ++k) if (k < wv) add += wsum[k];
    const int pre = add + v - s;
    P[2 * t] = pre;
    P[2 * t + 1] = pre + c0;
    if (t == 511) P[1024] = add + v;
    __syncthreads();

    for (int k = 0; k < c0; ++k) {
        int d = pre + k;
        if (d >= CAP) break;
        satoms[d] = atoms[g0 + k];
    }
    {
        int pre1 = pre + c0;
        for (int k = 0; k < c1; ++k) {
            int d = pre1 + k;
            if (d >= CAP) break;
            satoms[d] = atoms[g1 + k];
        }
    }
    __syncthreads();

    const int qz = t & 7, qy = (t >> 3) & 7, qx = t >> 6;
    const int cx0 = ox + (qx << 1), cy0 = oy + (qy << 1), cz0 = oz + (qz << 1);
    const float fcx = (float)cx0, fcy = (float)cy0, fcz = (float)cz0;

    float a000 = 0.0f, a001 = 0.0f, a010 = 0.0f, a011 = 0.0f;
    float a100 = 0.0f, a101 = 0.0f, a110 = 0.0f, a111 = 0.0f;

    int r = -1, i = 0, e = 0;
    while (i >= e) {
        if (++r >= 9) break;
        int dbx = r / 3, dby = r - dbx * 3;
        int bin0 = ((qx + dbx) * 10 + (qy + dby)) * 10 + qz;
        i = P[bin0];
        e = P[bin0 + 3];
        if (e > CAP) e = CAP;
    }
    while (r < 9) {
        float4 a = satoms[i];

        float ux = wrap128(a.x - fcx);
        float wx0 = bspline(ux);
        float wx1 = bspline(ux - 1.0f);
        float uy = wrap128(a.y - fcy);
        float wy0 = bspline(uy);
        float wy1 = bspline(uy - 1.0f);
        float uz = wrap128(a.z - fcz);
        float wz0 = bspline(uz);
        float wz1 = bspline(uz - 1.0f);
        float qs = a.w * (1.0f / 216.0f);
        float qx0 = qs * wx0, qx1 = qs * wx1;
        float m00 = qx0 * wy0, m01 = qx0 * wy1;
        float m10 = qx1 * wy0, m11 = qx1 * wy1;
        a000 += m00 * wz0; a001 += m00 * wz1;
        a010 += m01 * wz0; a011 += m01 * wz1;
        a100 += m10 * wz0; a101 += m10 * wz1;
        a110 += m11 * wz0; a111 += m11 * wz1;

        if (++i >= e) {
            while (i >= e) {
                if (++r >= 9) break;
                int dbx = r / 3, dby = r - dbx * 3;
                int bin0 = ((qx + dbx) * 10 + (qy + dby)) * 10 + qz;
                i = P[bin0];
                e = P[bin0 + 3];
                if (e > CAP) e = CAP;
            }
            if (r >= 9) break;
        }
    }

    *(float2*)&rmesh[((size_t)cx0       << 14) | ((size_t)cy0       << 7) | (size_t)cz0] = make_float2(a000, a001);
    *(float2*)&rmesh[((size_t)cx0       << 14) | ((size_t)(cy0 + 1) << 7) | (size_t)cz0] = make_float2(a010, a011);
    *(float2*)&rmesh[((size_t)(cx0 + 1) << 14) | ((size_t)cy0       << 7) | (size_t)cz0] = make_float2(a100, a101);
    *(float2*)&rmesh[((size_t)(cx0 + 1) << 14) | ((size_t)(cy0 + 1) << 7) | (size_t)cz0] = make_float2(a110, a111);
}

// ---------- LDS-staged gather: block = 16^3 cells, mesh halo 19^3 in LDS ----------

__global__ __launch_bounds__(512) void lds_gather_kernel(const float4* __restrict__ atoms,
                                                         const int* __restrict__ sortedIdx,
                                                         const int* __restrict__ offsets,
                                                         const float* __restrict__ rmesh,
                                                         float* __restrict__ out) {
    const int blk = blockIdx.x;                 // 8x8x8 tiles
    const int bz = blk & 7, by = (blk >> 3) & 7, bx = blk >> 6;
    const int ox = bx << 4, oy = by << 4, oz = bz << 4;

    __shared__ float tile[19][19][20];          // 28.9 KB (z-pitch 20)
    __shared__ int P[513];
    __shared__ int gbase[512];
    __shared__ int wsum[8];

    const int t = threadIdx.x;

    // stage mesh halo (cells ox-1 .. ox+17 per axis)
    for (int u = t; u < 19 * 19 * 19; u += 512) {
        int dz = u % 19, rest = u / 19;
        int dy = rest % 19, dx = rest / 19;
        int gx = (ox - 1 + dx) & 127;
        int gy = (oy - 1 + dy) & 127;
        int gz = (oz - 1 + dz) & 127;
        tile[dx][dy][dz] = rmesh[((size_t)gx << 14) | ((size_t)gy << 7) | (size_t)gz];
    }

    // this tile's 512 bins (aligned: 8 bins per edge)
    int cnt;
    {
        int uz = t & 7, uy = (t >> 3) & 7, ux = t >> 6;
        int gb = ((((bx << 3) | ux) << 6) | ((by << 3) | uy)) << 6 | ((bz << 3) | uz);
        int s0 = offsets[gb];
        gbase[t] = s0;
        cnt = offsets[gb + 1] - s0;
    }
    int lane = t & 63, wv = t >> 6;
    int v = cnt;
    #pragma unroll
    for (int d = 1; d < 64; d <<= 1) {
        int o = __shfl_up(v, d, 64);
        if (lane >= d) v += o;
    }
    if (lane == 63) wsum[wv] = v;
    __syncthreads();
    int add = 0;
    #pragma unroll
    for (int k = 0; k < 8; ++k) if (k < wv) add += wsum[k];
    P[t] = add + v - cnt;
    if (t == 511) P[512] = add + v;
    __syncthreads();

    const int total = P[512];
    for (int i = t; i < total; i += 512) {
        // binary search: P[j] <= i < P[j+1]
        int lo = 0, hi = 511;
        #pragma unroll
        for (int st = 0; st < 9; ++st) {
            int mid = (lo + hi + 1) >> 1;
            if (P[mid] <= i) lo = mid; else hi = mid - 1;
        }
        const int j = lo;
        const int src = gbase[j] + (i - P[j]);
        float4 a = atoms[src];

        float flx = floorf(a.x), fly = floorf(a.y), flz = floorf(a.z);
        int lx = (((int)flx) & 127) - ox + 1;   // in [1,16]
        int ly = (((int)fly) & 127) - oy + 1;
        int lz = (((int)flz) & 127) - oz + 1;
        float xx = a.x - flx, yy = a.y - fly, zz = a.z - flz;   // [0,1)

        float wx0 = bspline(xx + 1.0f), wx1 = bspline(xx);
        float wx2 = bspline(xx - 1.0f), wx3 = bspline(xx - 2.0f);
        float wy0 = bspline(yy + 1.0f), wy1 = bspline(yy);
        float wy2 = bspline(yy - 1.0f), wy3 = bspline(yy - 2.0f);
        float wz0 = bspline(zz + 1.0f), wz1 = bspline(zz);
        float wz2 = bspline(zz - 1.0f), wz3 = bspline(zz - 2.0f);

        float sum = 0.0f;
        #pragma unroll
        for (int di = 0; di < 4; ++di) {
            float wxv = (di == 0) ? wx0 : (di == 1) ? wx1 : (di == 2) ? wx2 : wx3;
            const float* rowx = &tile[lx - 1 + di][0][0];
            float sy = 0.0f;
            #pragma unroll
            for (int dj = 0; dj < 4; ++dj) {
                float wyv = (dj == 0) ? wy0 : (dj == 1) ? wy1 : (dj == 2) ? wy2 : wy3;
                const float* rowz = rowx + (ly - 1 + dj) * 20 + (lz - 1);
                float sz = wz0 * rowz[0] + wz1 * rowz[1] + wz2 * rowz[2] + wz3 * rowz[3];
                sy += wyv * sz;
            }
            sum += wxv * sy;
        }
        out[sortedIdx[src]] = sum * (1.0f / 216.0f) - a.w * 0.79788456080286535588f;
    }
}

// ---------- register-shuffle 128-pt FFT (wave per line) ----------

__device__ inline void bfly_dif(float& rr, float& ii, int h, bool hi, float cs, float sn) {
    float pr = __shfl_xor(rr, h), pi = __shfl_xor(ii, h);
    float br = hi ? (pr - rr) : (rr + pr);
    float bi = hi ? (pi - ii) : (ii + pi);
    rr = cs * br - sn * bi;
    ii = cs * bi + sn * br;
}

__device__ inline void bfly_dit(float& rr, float& ii, int h, bool hi, float cs, float sn) {
    float pr = __shfl_xor(rr, h), pi = __shfl_xor(ii, h);
    float xr = hi ? rr : pr, xi = hi ? ii : pi;
    float br = hi ? pr : rr, bi = hi ? pi : ii;
    float tr = cs * xr - sn * xi, ti = cs * xi + sn * xr;
    rr = hi ? (br - tr) : (br + tr);
    ii = hi ? (bi - ti) : (bi + ti);
}

__device__ inline void wfft_dif_fwd(float& r0, float& i0, float& r1, float& i1, int lane) {
    {
        float ang = -PI_F * (float)lane * (1.0f / 64.0f);
        float sn, cs; __sincosf(ang, &sn, &cs);
        float ar = r0 + r1, ai = i0 + i1;
        float dr = r0 - r1, di = i0 - i1;
        r0 = ar; i0 = ai;
        r1 = cs * dr - sn * di;
        i1 = cs * di + sn * dr;
    }
    #pragma unroll
    for (int h = 32; h >= 1; h >>= 1) {
        int pos = lane & (h - 1);
        bool hi = (lane & h) != 0;
        float ang = hi ? (-PI_F * (float)pos / (float)h) : 0.0f;
        float sn, cs; __sincosf(ang, &sn, &cs);
        bfly_dif(r0, i0, h, hi, cs, sn);
        bfly_dif(r1, i1, h, hi, cs, sn);
    }
}

__device__ inline void wfft_dit_inv(float& r0, float& i0, float& r1, float& i1, int lane) {
    #pragma unroll
    for (int h = 1; h <= 32; h <<= 1) {
        int pos = lane & (h - 1);
        bool hi = (lane & h) != 0;
        float ang = PI_F * (float)pos / (float)h;
        float sn, cs; __sincosf(ang, &sn, &cs);
        bfly_dit(r0, i0, h, hi, cs, sn);
        bfly_dit(r1, i1, h, hi, cs, sn);
    }
    {
        float ang = PI_F * (float)lane * (1.0f / 64.0f);
        float sn, cs; __sincosf(ang, &sn, &cs);
        float tr = cs * r1 - sn * i1, ti = cs * i1 + sn * r1;
        float nr = r0 + tr, ni = i0 + ti;
        r1 = r0 - tr; i1 = i0 - ti;
        r0 = nr; i0 = ni;
    }
}

// ---------- z forward: real -> complex natural order (Hermitian prefix) ----------

__global__ __launch_bounds__(1024) void fftZfwd(const float* __restrict__ rin,
                                                float2* __restrict__ mesh) {
    __shared__ float tre[16][132], tim[16][132];
    const int t = threadIdx.x, b = blockIdx.x;
    for (int u = t; u < 2048; u += 1024) {
        int l = u >> 7, e = u & 127;
        tre[l][e] = rin[((size_t)((b << 4) | l) << 7) + e];
    }
    __syncthreads();
    const int w = t >> 6, lane = t & 63;
    float r0 = tre[w][lane],      i0 = 0.0f;
    float r1 = tre[w][lane + 64], i1 = 0.0f;
    wfft_dif_fwd(r0, i0, r1, i1, lane);
    int e0 = (int)(__brev((unsigned)lane) >> 25);
    tre[w][e0] = r0;     tim[w][e0] = i0;
    tre[w][e0 + 1] = r1; tim[w][e0 + 1] = i1;
    __syncthreads();
    for (int u = t; u < 2048; u += 1024) {
        int l = u >> 7, e = u & 127;
        if (e < ZP)
            mesh[(size_t)((b << 4) | l) * ZP + e] = make_float2(tre[l][e], tim[l][e]);
    }
}

// ---------- y forward: natural in -> bit-reversed positions ----------

__global__ __launch_bounds__(512) void fftYfwd(float2* __restrict__ mesh) {
    __shared__ float tre[8][132], tim[8][132];
    const int t = threadIdx.x, b = blockIdx.x;
    const int x = b & 127, zf0 = (b >> 7) << 3;
    const size_t rb = ((size_t)(x << 7)) * ZP + zf0;
    for (int u = t; u < 1024; u += 512) {
        int e = u >> 3, dz = u & 7;
        float2 vv = mesh[rb + (size_t)e * ZP + dz];
        tre[dz][e] = vv.x; tim[dz][e] = vv.y;
    }
    __syncthreads();
    const int w = t >> 6, lane = t & 63;
    float r0 = tre[w][lane],      i0 = tim[w][lane];
    float r1 = tre[w][lane + 64], i1 = tim[w][lane + 64];
    wfft_dif_fwd(r0, i0, r1, i1, lane);
    tre[w][lane] = r0;      tim[w][lane] = i0;
    tre[w][lane + 64] = r1; tim[w][lane + 64] = i1;
    __syncthreads();
    for (int u = t; u < 1024; u += 512) {
        int e = u >> 3, dz = u & 7;
        mesh[rb + (size_t)e * ZP + dz] = make_float2(tre[dz][e], tim[dz][e]);
    }
}

// ---------- fused x: DIF fwd -> G(k) at rev-indexed k -> DIT inv ----------

__global__ __launch_bounds__(512) void fftXGw(float2* __restrict__ mesh,
                                              const float* __restrict__ cell) {
    __shared__ float tre[8][132], tim[8][132];
    const int t = threadIdx.x, b = blockIdx.x;
    const int py = b & 127, zf0 = (b >> 7) << 3;
    for (int u = t; u < 1024; u += 512) {
        int e = u >> 3, dz = u & 7;
        float2 vv = mesh[(size_t)((e << 7) | py) * ZP + zf0 + dz];
        tre[dz][e] = vv.x; tim[dz][e] = vv.y;
    }
    __syncthreads();
    const int w = t >> 6, lane = t & 63;
    float r0 = tre[w][lane],      i0 = tim[w][lane];
    float r1 = tre[w][lane + 64], i1 = tim[w][lane + 64];
    wfft_dif_fwd(r0, i0, r1, i1, lane);
    {
        float inv[9]; float det; inv3x3(cell, inv, &det);
        float invVol = 1.0f / fabsf(det);
        int my = (int)(__brev((unsigned)py) >> 25);
        int mz = zf0 + w;
        float fy = (my < 64) ? (float)my : (float)(my - 128);
        float fz = (mz < 64) ? (float)mz : (float)(mz - 128);
        int mx0 = (int)(__brev((unsigned)lane) >> 25);
        #pragma unroll
        for (int s = 0; s < 2; ++s) {
            int mx = mx0 + s;
            float fx = (mx < 64) ? (float)mx : (float)(mx - 128);
            float kx = TWO_PI_F * (fx * inv[0] + fy * inv[1] + fz * inv[2]);
            float ky = TWO_PI_F * (fx * inv[3] + fy * inv[4] + fz * inv[5]);
            float kz = TWO_PI_F * (fx * inv[6] + fy * inv[7] + fz * inv[8]);
            float ksq = kx * kx + ky * ky + kz * kz;
            float G = (ksq == 0.0f) ? 0.0f
                      : FOUR_PI_F / ksq * __expf(-0.5f * ksq) * invVol;
            if (s == 0) { r0 *= G; i0 *= G; } else { r1 *= G; i1 *= G; }
        }
    }
    wfft_dit_inv(r0, i0, r1, i1, lane);
    tre[w][lane] = r0;      tim[w][lane] = i0;
    tre[w][lane + 64] = r1; tim[w][lane + 64] = i1;
    __syncthreads();
    for (int u = t; u < 1024; u += 512) {
        int e = u >> 3, dz = u & 7;
        mesh[(size_t)((e << 7) | py) * ZP + zf0 + dz] =
            make_float2(tre[dz][e], tim[dz][e]);
    }
}

// ---------- y inverse: bit-reversed positions in -> natural out ----------

__global__ __launch_bounds__(512) void fftYinv(float2* __restrict__ mesh) {
    __shared__ float tre[8][132], tim[8][132];
    const int t = threadIdx.x, b = blockIdx.x;
    const int x = b & 127, zf0 = (b >> 7) << 3;
    const size_t rb = ((size_t)(x << 7)) * ZP + zf0;
    for (int u = t; u < 1024; u += 512) {
        int e = u >> 3, dz = u & 7;
        float2 vv = mesh[rb + (size_t)e * ZP + dz];
        tre[dz][e] = vv.x; tim[dz][e] = vv.y;
    }
    __syncthreads();
    const int w = t >> 6, lane = t & 63;
    float r0 = tre[w][lane],      i0 = tim[w][lane];
    float r1 = tre[w][lane + 64], i1 = tim[w][lane + 64];
    wfft_dit_inv(r0, i0, r1, i1, lane);
    tre[w][lane] = r0;      tim[w][lane] = i0;
    tre[w][lane + 64] = r1; tim[w][lane + 64] = i1;
    __syncthreads();
    for (int u = t; u < 1024; u += 512) {
        int e = u >> 3, dz = u & 7;
        mesh[rb + (size_t)e * ZP + dz] = make_float2(tre[dz][e], tim[dz][e]);
    }
}

// ---------- z inverse: Hermitian mirror -> real out ----------

__global__ __launch_bounds__(1024) void fftZinv(const float2* __restrict__ mesh,
                                                float* __restrict__ rout) {
    __shared__ float tre[16][132], tim[16][132];
    const int t = threadIdx.x, b = blockIdx.x;
    for (int u = t; u < 2048; u += 1024) {
        int l = u >> 7, e = u & 127;
        int src = (e <= 64) ? e : 128 - e;
        float2 vv = mesh[(size_t)((b << 4) | l) * ZP + src];
        tre[l][e] = vv.x;
        tim[l][e] = (e <= 64) ? vv.y : -vv.y;
    }
    __syncthreads();
    const int w = t >> 6, lane = t & 63;
    int e0 = (int)(__brev((unsigned)lane) >> 25);
    float r0 = tre[w][e0],     i0 = tim[w][e0];
    float r1 = tre[w][e0 + 1], i1 = tim[w][e0 + 1];
    wfft_dit_inv(r0, i0, r1, i1, lane);
    const size_t rb = ((size_t)((b << 4) | w) << 7);
    rout[rb + lane] = r0;
    rout[rb + lane + 64] = r1;
}

// ---------- launch ----------

extern "C" void kernel_launch(void* const* d_in, const int* in_sizes, int n_in,
                              void* d_out, int out_size, void* d_ws, size_t ws_size,
                              hipStream_t stream) {
    const float* cell = (const float*)d_in[0];
    const float* pos  = (const float*)d_in[1];
    const float* q    = (const float*)d_in[2];
    float* out = (float*)d_out;
    const int n = in_sizes[2];

    char* ws = (char*)d_ws;
    size_t o = 0;
    float4* sorted   = (float4*)(ws + o); o += (size_t)n * 16;
    int* sortedIdx   = (int*)(ws + o);    o += (size_t)n * 4;  o = (o + 255) & ~(size_t)255;
    int* hist        = (int*)(ws + o);    o += (size_t)BINS * 4;            // also reorder cursor
    int* offsets     = (int*)(ws + o);    o += (size_t)(BINS + 4) * 4;
    int* partials    = (int*)(ws + o);    o += (size_t)SCAN_BLOCKS * 4; o = (o + 255) & ~(size_t)255;
    float2* mesh     = (float2*)(ws + o); o += (size_t)128 * 128 * ZP * 8;  // 9.4 MB
    float* rmesh     = (float*)(ws + o);  // NTOT * 4 = 8 MB

    zero_int_kernel<<<BINS / 256, 256, 0, stream>>>(hist, BINS);
    hist_kernel<<<(n + 255) / 256, 256, 0, stream>>>(cell, pos, hist, n);
    scan_local<<<SCAN_BLOCKS, 256, 0, stream>>>((const int4*)hist, (int4*)offsets, partials);
    scan_add<<<SCAN_BLOCKS, 256, 0, stream>>>((int4*)hist, (int4*)offsets, partials, offsets);
    reorder_kernel<<<(n + 255) / 256, 256, 0, stream>>>(cell, pos, q, hist, sorted, sortedIdx, n);

    lds_scatter_kernel<<<512, 512, 0, stream>>>(sorted, offsets, rmesh);

    fftZfwd<<<1024, 1024, 0, stream>>>(rmesh, mesh);
    fftYfwd<<<9 * 128, 512, 0, stream>>>(mesh);
    fftXGw<<<9 * 128, 512, 0, stream>>>(mesh, cell);
    fftYinv<<<9 * 128, 512, 0, stream>>>(mesh);
    fftZinv<<<1024, 1024, 0, stream>>>(mesh, rmesh);

    lds_gather_kernel<<<512, 512, 0, stream>>>(sorted, sortedIdx, offsets, rmesh, out);
}